// Round 6
// baseline (393.135 us; speedup 1.0000x reference)
//
#include <hip/hip_runtime.h>

#define D 128
typedef __attribute__((ext_vector_type(8))) short short8;
typedef __attribute__((ext_vector_type(4))) float f32x4;

__device__ __forceinline__ float leaky(float x){ return x >= 0.f ? x : 0.01f*x; }
__device__ __forceinline__ unsigned short f2bf(float x){
    unsigned u = __float_as_uint(x);
    u = (u + 0x7fffu + ((u>>16)&1u)) >> 16;
    return (unsigned short)u;
}

// fold attention vectors + convert W1/W2 to bf16
__global__ void k_prep(const float* __restrict__ Ww, const float* __restrict__ Wb,
                       const float* __restrict__ a, float* __restrict__ v,
                       const float* __restrict__ W1, const float* __restrict__ W2,
                       unsigned short* __restrict__ W1b, unsigned short* __restrict__ W2b){
    int b = blockIdx.x;
    if(b < 64){
        int i = b*256 + threadIdx.x; // 0..16383
        W1b[i] = f2bf(W1[i]);
        W2b[i] = f2bf(W2[i]);
        return;
    }
    int i = threadIdx.x; if(i >= 128) return;
    float vs=0.f, vd=0.f;
    for (int o=0;o<D;++o){ float w = Ww[o*D+i]; vs = fmaf(w, a[o], vs); vd = fmaf(w, a[D+o], vd); }
    v[i]=vs; v[D+i]=vd;
    if(i==0){
        float cs=0.f,cd=0.f;
        for(int o=0;o<D;++o){ cs=fmaf(Wb[o],a[o],cs); cd=fmaf(Wb[o],a[D+o],cd); }
        v[256]=cs; v[257]=cd;
    }
}

// H_perm = bf16(F @ W1^T + b1) (permuted c' = (c&15)*8 + (c>>4)) + attention scalars ss/sd
__global__ __launch_bounds__(256) void k_msgscal(const float* __restrict__ F,
        const unsigned short* __restrict__ W1b, const float* __restrict__ b1,
        const float* __restrict__ v, unsigned short* __restrict__ Hp,
        float* __restrict__ ss, float* __restrict__ sd, int N){
    const int lane = threadIdx.x & 63;
    const int wid  = blockIdx.x*4 + (threadIdx.x>>6);
    const int nw   = gridDim.x*4;
    const int t = lane & 15, g = lane >> 4;
    short8 wf[4][8];
    #pragma unroll
    for(int kk=0;kk<4;++kk)
      #pragma unroll
      for(int j=0;j<8;++j)
        wf[kk][j] = *(const short8*)(W1b + (size_t)(j*16+t)*D + kk*32 + g*8);
    float bb[8];
    #pragma unroll
    for(int j=0;j<8;++j) bb[j] = b1[j*16+t];
    const float c_s = v[256], c_d = v[257];
    const int Mt = (N+15)>>4;
    for(int rt = wid; rt < Mt; rt += nw){
        int row0 = rt*16 + t;
        int row = row0 < N ? row0 : N-1;
        const float* fr = F + (size_t)row*D + g*8;
        f32x4 acc[8];
        #pragma unroll
        for(int j=0;j<8;++j) acc[j] = (f32x4){0.f,0.f,0.f,0.f};
        float ds = 0.f, dd = 0.f;
        #pragma unroll
        for(int kk=0;kk<4;++kk){
            f32x4 lo = *(const f32x4*)(fr + kk*32);
            f32x4 hi = *(const f32x4*)(fr + kk*32 + 4);
            f32x4 vsl = *(const f32x4*)(v + kk*32 + g*8);
            f32x4 vsh = *(const f32x4*)(v + kk*32 + g*8 + 4);
            f32x4 vdl = *(const f32x4*)(v + D + kk*32 + g*8);
            f32x4 vdh = *(const f32x4*)(v + D + kk*32 + g*8 + 4);
            #pragma unroll
            for(int q=0;q<4;++q){
                ds = fmaf(lo[q], vsl[q], ds); ds = fmaf(hi[q], vsh[q], ds);
                dd = fmaf(lo[q], vdl[q], dd); dd = fmaf(hi[q], vdh[q], dd);
            }
            short8 af;
            af[0]=(short)f2bf(lo[0]); af[1]=(short)f2bf(lo[1]);
            af[2]=(short)f2bf(lo[2]); af[3]=(short)f2bf(lo[3]);
            af[4]=(short)f2bf(hi[0]); af[5]=(short)f2bf(hi[1]);
            af[6]=(short)f2bf(hi[2]); af[7]=(short)f2bf(hi[3]);
            #pragma unroll
            for(int j=0;j<8;++j)
                acc[j] = __builtin_amdgcn_mfma_f32_16x16x32_bf16(af, wf[kk][j], acc[j], 0,0,0);
        }
        ds += __shfl_xor(ds,16); ds += __shfl_xor(ds,32);
        dd += __shfl_xor(dd,16); dd += __shfl_xor(dd,32);
        if(g==0 && row0 < N){ ss[row0] = ds + c_s; sd[row0] = dd + c_d; }
        #pragma unroll
        for(int r=0;r<4;++r){
            int rr = rt*16 + g*4 + r;
            if(rr < N){
                short8 h;
                #pragma unroll
                for(int j=0;j<8;++j) h[j] = (short)f2bf(acc[j][r] + bb[j]);
                *(short8*)(Hp + (size_t)rr*D + t*8) = h;
            }
        }
    }
}

// P1: per-block LDS histogram over coarse buckets (dst>>6); M[bucket][blk]
__global__ __launch_bounds__(256) void k_bcount(const int* __restrict__ dst,
        unsigned* __restrict__ M, int E, int NB, int CHUNK){
    __shared__ unsigned h[1600];
    for(int i=threadIdx.x;i<NB;i+=256) h[i]=0u;
    __syncthreads();
    int s = blockIdx.x*CHUNK;
    int e = s+CHUNK < E ? s+CHUNK : E;
    for(int i=s+(int)threadIdx.x;i<e;i+=256) atomicAdd(&h[((unsigned)dst[i])>>6],1u);
    __syncthreads();
    for(int i=threadIdx.x;i<NB;i+=256) M[(size_t)i*gridDim.x + blockIdx.x] = h[i];
}

// P2: exclusive scan, 2048/block, redundant block prefix (no inter-block dep)
__global__ void k_scan8(const unsigned* __restrict__ cnt, unsigned* __restrict__ off, int n){
    int b = blockIdx.x, t = threadIdx.x; // 256 threads
    int base = b*2048;
    __shared__ unsigned lds[256];
    unsigned s = 0;
    for(int j=t; j<base; j+=256) s += cnt[j];
    #pragma unroll
    for(int o=1;o<64;o<<=1) s += __shfl_xor(s,o);
    if((t&63)==0) lds[t>>6] = s;
    __syncthreads();
    unsigned prefix = lds[0]+lds[1]+lds[2]+lds[3];
    __syncthreads();
    unsigned v[8]; unsigned tsum=0;
    #pragma unroll
    for(int k=0;k<8;++k){ int i = base + t*8 + k; v[k] = (i<n)?cnt[i]:0u; tsum += v[k]; }
    unsigned x = tsum;
    #pragma unroll
    for(int o=1;o<64;o<<=1){ unsigned y = __shfl_up(x,(unsigned)o); if((t&63)>=o) x += y; }
    if((t&63)==63) lds[t>>6] = x;
    __syncthreads();
    unsigned waveoff = 0;
    for(int w=0; w<(t>>6); ++w) waveoff += lds[w];
    unsigned run = prefix + waveoff + (x - tsum);
    #pragma unroll
    for(int k=0;k<8;++k){
        int i = base + t*8 + k;
        if(i<n) off[i] = run;
        else if(i==n) off[n] = run;
        run += v[k];
    }
}

// P3: bucket-partition edges; slots via LDS atomics on scanned per-(block,bucket) bases
__global__ __launch_bounds__(256) void k_bscatter(const int* __restrict__ src,
        const int* __restrict__ dst, const unsigned* __restrict__ Msc,
        uint2* __restrict__ ew, int E, int NB, int CHUNK){
    __shared__ unsigned hoff[1600];
    int blk = blockIdx.x, NBLKg = gridDim.x;
    for(int i=threadIdx.x;i<NB;i+=256) hoff[i] = Msc[(size_t)i*NBLKg + blk];
    __syncthreads();
    int s = blk*CHUNK;
    int e = s+CHUNK < E ? s+CHUNK : E;
    for(int i=s+(int)threadIdx.x;i<e;i+=256){
        int d = dst[i];
        unsigned p = atomicAdd(&hoff[((unsigned)d)>>6], 1u);
        ew[p] = make_uint2((unsigned)src[i], (unsigned)d);
    }
}

// P4: per-bucket fine CSR (64 dsts): LDS count -> wave scan -> LDS-atomic rank
__global__ __launch_bounds__(256) void k_fine(const uint2* __restrict__ ew,
        const unsigned* __restrict__ Msc, unsigned* __restrict__ esrc,
        unsigned* __restrict__ offs, int N, int NB, int NBLKg, int E){
    __shared__ unsigned cA[64], cB[64], loff[64];
    __shared__ unsigned begS, endS;
    int b = blockIdx.x;
    int dbase = b<<6;
    if(threadIdx.x==0){
        begS = Msc[(size_t)b*NBLKg];
        endS = (b+1 < NB) ? Msc[(size_t)(b+1)*NBLKg] : (unsigned)E;
    }
    if(threadIdx.x<64){ cA[threadIdx.x]=0u; cB[threadIdx.x]=0u; }
    __syncthreads();
    const unsigned beg = begS, end = endS;
    for(unsigned i=beg+threadIdx.x; i<end; i+=256)
        atomicAdd(&cA[ew[i].y & 63], 1u);
    __syncthreads();
    if(threadIdx.x<64){
        unsigned c = cA[threadIdx.x];
        unsigned x = c;
        #pragma unroll
        for(int o=1;o<64;o<<=1){ unsigned y = __shfl_up(x,(unsigned)o); if((int)threadIdx.x>=o) x += y; }
        loff[threadIdx.x] = x - c;
        int dd = dbase + (int)threadIdx.x;
        if(dd < N) offs[dd] = beg + x - c;
    }
    if(b==0 && threadIdx.x==64) offs[N] = (unsigned)E;
    __syncthreads();
    for(unsigned i=beg+threadIdx.x; i<end; i+=256){
        uint2 p = ew[i];
        unsigned dl = p.y & 63;
        unsigned r = atomicAdd(&cB[dl], 1u);
        esrc[beg + loff[dl] + r] = p.x;
    }
}

// fused gather: 4 edges/iter, 16 lanes/edge, 16B/lane; 2-deep pipeline
__global__ __launch_bounds__(256) void k_gather(const unsigned* __restrict__ off,
        const unsigned* __restrict__ esrc, const float* __restrict__ ss,
        const float* __restrict__ sdv, const unsigned short* __restrict__ Hp,
        float* __restrict__ out, int N){
    const int wv = threadIdx.x>>6, l = threadIdx.x&63;
    const int d = blockIdx.x*4 + wv;
    if(d>=N) return;
    const int g = l>>4, t = l&15;
    const unsigned kb = off[d], ke = off[d+1];
    const float sdd = sdv[d];
    float acc[8];
    #pragma unroll
    for(int j=0;j<8;++j) acc[j]=0.f;
    float den = 0.f;

    unsigned eA = kb + g;
    unsigned eB = eA + 4;
    bool vA = eA < ke, vB = eB < ke;
    float ssA=0.f, ssB=0.f;
    uint4 uA = make_uint4(0u,0u,0u,0u), uB = make_uint4(0u,0u,0u,0u);
    if(vA){ unsigned s=esrc[eA]; ssA=ss[s]; uA=*(const uint4*)(Hp+(size_t)s*D+t*8); }
    if(vB){ unsigned s=esrc[eB]; ssB=ss[s]; uB=*(const uint4*)(Hp+(size_t)s*D+t*8); }
    while(vA){
        unsigned eC = eB + 4;
        bool vC = eC < ke;
        float ssC = 0.f; uint4 uC = make_uint4(0u,0u,0u,0u);
        if(vC){ unsigned s=esrc[eC]; ssC=ss[s]; uC=*(const uint4*)(Hp+(size_t)s*D+t*8); }
        float w = __expf(leaky(ssA + sdd));
        acc[0] = fmaf(w, __uint_as_float(uA.x<<16),        acc[0]);
        acc[1] = fmaf(w, __uint_as_float(uA.x&0xffff0000u),acc[1]);
        acc[2] = fmaf(w, __uint_as_float(uA.y<<16),        acc[2]);
        acc[3] = fmaf(w, __uint_as_float(uA.y&0xffff0000u),acc[3]);
        acc[4] = fmaf(w, __uint_as_float(uA.z<<16),        acc[4]);
        acc[5] = fmaf(w, __uint_as_float(uA.z&0xffff0000u),acc[5]);
        acc[6] = fmaf(w, __uint_as_float(uA.w<<16),        acc[6]);
        acc[7] = fmaf(w, __uint_as_float(uA.w&0xffff0000u),acc[7]);
        den += w;
        vA = vB; ssA = ssB; uA = uB;
        vB = vC; ssB = ssC; uB = uC;
        eB = eC;
    }
    #pragma unroll
    for(int j=0;j<8;++j){
        acc[j] += __shfl_xor(acc[j],16);
        acc[j] += __shfl_xor(acc[j],32);
    }
    den += __shfl_xor(den,16);
    den += __shfl_xor(den,32);
    float inv = 1.f/(den + 1e-9f);
    int c = g*32 + t;
    out[(size_t)d*D + c]      = acc[g*2]  * inv;
    out[(size_t)d*D + c + 16] = acc[g*2+1]* inv;
}

// out = leaky(f + h + (f*h)@W2^T + b2), in place on out
__global__ __launch_bounds__(256) void k_final(const float* __restrict__ F,
        const unsigned short* __restrict__ W2b, const float* __restrict__ b2,
        float* __restrict__ out, int N){
    const int lane = threadIdx.x & 63;
    const int wid  = blockIdx.x*4 + (threadIdx.x>>6);
    const int nw   = gridDim.x*4;
    const int t = lane & 15, g = lane >> 4;
    short8 wf[4][8];
    #pragma unroll
    for(int kk=0;kk<4;++kk)
      #pragma unroll
      for(int j=0;j<8;++j)
        wf[kk][j] = *(const short8*)(W2b + (size_t)(j*16+t)*D + kk*32 + g*8);
    float bb[8];
    #pragma unroll
    for(int j=0;j<8;++j) bb[j] = b2[j*16+t];
    const int Mt = (N+15)>>4;
    for(int rt = wid; rt < Mt; rt += nw){
        int row = rt*16 + t; if(row>=N) row = N-1;
        const float* fr = F   + (size_t)row*D + g*8;
        const float* hr = out + (size_t)row*D + g*8;
        f32x4 acc[8];
        #pragma unroll
        for(int j=0;j<8;++j) acc[j] = (f32x4){0.f,0.f,0.f,0.f};
        #pragma unroll
        for(int kk=0;kk<4;++kk){
            f32x4 flo = *(const f32x4*)(fr + kk*32);
            f32x4 fhi = *(const f32x4*)(fr + kk*32 + 4);
            f32x4 hlo = *(const f32x4*)(hr + kk*32);
            f32x4 hhi = *(const f32x4*)(hr + kk*32 + 4);
            short8 af;
            af[0]=(short)f2bf(flo[0]*hlo[0]); af[1]=(short)f2bf(flo[1]*hlo[1]);
            af[2]=(short)f2bf(flo[2]*hlo[2]); af[3]=(short)f2bf(flo[3]*hlo[3]);
            af[4]=(short)f2bf(fhi[0]*hhi[0]); af[5]=(short)f2bf(fhi[1]*hhi[1]);
            af[6]=(short)f2bf(fhi[2]*hhi[2]); af[7]=(short)f2bf(fhi[3]*hhi[3]);
            #pragma unroll
            for(int j=0;j<8;++j)
                acc[j] = __builtin_amdgcn_mfma_f32_16x16x32_bf16(af, wf[kk][j], acc[j], 0,0,0);
        }
        #pragma unroll
        for(int r=0;r<4;++r){
            int rr = rt*16 + g*4 + r;
            if(rr < N){
                #pragma unroll
                for(int j=0;j<8;++j){
                    int c = j*16 + t;
                    float f = F[(size_t)rr*D + c];
                    float h = out[(size_t)rr*D + c];
                    float val = f + h + acc[j][r] + bb[j];
                    out[(size_t)rr*D + c] = leaky(val);
                }
            }
        }
    }
}

extern "C" void kernel_launch(void* const* d_in, const int* in_sizes, int n_in,
                              void* d_out, int out_size, void* d_ws, size_t ws_size,
                              hipStream_t stream) {
    const int*   idx  = (const int*)  d_in[0];   // (2,E)
    const float* F    = (const float*)d_in[1];   // (N,128)
    const float* Waw  = (const float*)d_in[3];
    const float* Wab  = (const float*)d_in[4];
    const float* W1w  = (const float*)d_in[5];
    const float* W1b  = (const float*)d_in[6];
    const float* W2w  = (const float*)d_in[7];
    const float* W2b  = (const float*)d_in[8];
    const float* a    = (const float*)d_in[9];
    float* out = (float*)d_out;

    const int E = in_sizes[0]/2;
    const int N = in_sizes[1]/D;
    const int* srcp = idx;
    const int* dstp = idx + E;

    const int NBLK = 256;
    const int CHUNK = (E + NBLK - 1)/NBLK;
    const int NB = (N + 63)/64;            // coarse buckets (<=1600 by construction)
    const int NT = NB*NBLK;

    unsigned short* Hp  = (unsigned short*)d_ws;           // N*128 bf16 (permuted rows)
    unsigned short* W1c = Hp + (size_t)N*D;                // 16384
    unsigned short* W2c = W1c + 16384;                     // 16384
    float*    ss   = (float*)(W2c + 16384);                // N
    float*    sd   = ss + N;                               // N
    float*    v    = sd + N;                               // 320
    unsigned* M    = (unsigned*)(v + 320);                 // NT
    unsigned* Msc  = M + NT;                               // NT+2
    unsigned* offs = Msc + NT + 2;                         // N+2
    unsigned* esrc = offs + (N+2);                         // E
    uint2*    ew   = (uint2*)(esrc + E + 2);               // E  (8B aligned: offsets even)

    k_prep    <<<65, 256, 0, stream>>>(Waw, Wab, a, v, W1w, W2w, W1c, W2c);
    k_msgscal <<<512, 256, 0, stream>>>(F, W1c, W1b, v, Hp, ss, sd, N);
    k_bcount  <<<NBLK, 256, 0, stream>>>(dstp, M, E, NB, CHUNK);
    k_scan8   <<<(NT+1+2047)/2048, 256, 0, stream>>>(M, Msc, NT);
    k_bscatter<<<NBLK, 256, 0, stream>>>(srcp, dstp, Msc, ew, E, NB, CHUNK);
    k_fine    <<<NB, 256, 0, stream>>>(ew, Msc, esrc, offs, N, NB, NBLK, E);
    k_gather  <<<(N+3)/4, 256, 0, stream>>>(offs, esrc, ss, sd, Hp, out, N);
    k_final   <<<512, 256, 0, stream>>>(F, W2c, W2b, out, N);
}

// Round 7
// 202.849 us; speedup vs baseline: 1.9381x; 1.9381x over previous
//
#include <hip/hip_runtime.h>

#define D 128
typedef __attribute__((ext_vector_type(8))) short short8;
typedef __attribute__((ext_vector_type(4))) float f32x4;

__device__ __forceinline__ float leaky(float x){ return x >= 0.f ? x : 0.01f*x; }
__device__ __forceinline__ unsigned short f2bf(float x){
    unsigned u = __float_as_uint(x);
    u = (u + 0x7fffu + ((u>>16)&1u)) >> 16;
    return (unsigned short)u;
}

// fold attention vectors + convert W1/W2 to bf16
__global__ void k_prep(const float* __restrict__ Ww, const float* __restrict__ Wb,
                       const float* __restrict__ a, float* __restrict__ v,
                       const float* __restrict__ W1, const float* __restrict__ W2,
                       unsigned short* __restrict__ W1b, unsigned short* __restrict__ W2b){
    int b = blockIdx.x;
    if(b < 64){
        int i = b*256 + threadIdx.x; // 0..16383
        W1b[i] = f2bf(W1[i]);
        W2b[i] = f2bf(W2[i]);
        return;
    }
    int i = threadIdx.x; if(i >= 128) return;
    float vs=0.f, vd=0.f;
    for (int o=0;o<D;++o){ float w = Ww[o*D+i]; vs = fmaf(w, a[o], vs); vd = fmaf(w, a[D+o], vd); }
    v[i]=vs; v[D+i]=vd;
    if(i==0){
        float cs=0.f,cd=0.f;
        for(int o=0;o<D;++o){ cs=fmaf(Wb[o],a[o],cs); cd=fmaf(Wb[o],a[D+o],cd); }
        v[256]=cs; v[257]=cd;
    }
}

// H_perm = bf16(F @ W1^T + b1) (permuted c' = (c&15)*8 + (c>>4)) + attention scalars ss/sd
__global__ __launch_bounds__(256) void k_msgscal(const float* __restrict__ F,
        const unsigned short* __restrict__ W1b, const float* __restrict__ b1,
        const float* __restrict__ v, unsigned short* __restrict__ Hp,
        float* __restrict__ ss, float* __restrict__ sd, int N){
    const int lane = threadIdx.x & 63;
    const int wid  = blockIdx.x*4 + (threadIdx.x>>6);
    const int nw   = gridDim.x*4;
    const int t = lane & 15, g = lane >> 4;
    short8 wf[4][8];
    #pragma unroll
    for(int kk=0;kk<4;++kk)
      #pragma unroll
      for(int j=0;j<8;++j)
        wf[kk][j] = *(const short8*)(W1b + (size_t)(j*16+t)*D + kk*32 + g*8);
    float bb[8];
    #pragma unroll
    for(int j=0;j<8;++j) bb[j] = b1[j*16+t];
    const float c_s = v[256], c_d = v[257];
    const int Mt = (N+15)>>4;
    for(int rt = wid; rt < Mt; rt += nw){
        int row0 = rt*16 + t;
        int row = row0 < N ? row0 : N-1;
        const float* fr = F + (size_t)row*D + g*8;
        f32x4 acc[8];
        #pragma unroll
        for(int j=0;j<8;++j) acc[j] = (f32x4){0.f,0.f,0.f,0.f};
        float ds = 0.f, dd = 0.f;
        #pragma unroll
        for(int kk=0;kk<4;++kk){
            f32x4 lo = *(const f32x4*)(fr + kk*32);
            f32x4 hi = *(const f32x4*)(fr + kk*32 + 4);
            f32x4 vsl = *(const f32x4*)(v + kk*32 + g*8);
            f32x4 vsh = *(const f32x4*)(v + kk*32 + g*8 + 4);
            f32x4 vdl = *(const f32x4*)(v + D + kk*32 + g*8);
            f32x4 vdh = *(const f32x4*)(v + D + kk*32 + g*8 + 4);
            #pragma unroll
            for(int q=0;q<4;++q){
                ds = fmaf(lo[q], vsl[q], ds); ds = fmaf(hi[q], vsh[q], ds);
                dd = fmaf(lo[q], vdl[q], dd); dd = fmaf(hi[q], vdh[q], dd);
            }
            short8 af;
            af[0]=(short)f2bf(lo[0]); af[1]=(short)f2bf(lo[1]);
            af[2]=(short)f2bf(lo[2]); af[3]=(short)f2bf(lo[3]);
            af[4]=(short)f2bf(hi[0]); af[5]=(short)f2bf(hi[1]);
            af[6]=(short)f2bf(hi[2]); af[7]=(short)f2bf(hi[3]);
            #pragma unroll
            for(int j=0;j<8;++j)
                acc[j] = __builtin_amdgcn_mfma_f32_16x16x32_bf16(af, wf[kk][j], acc[j], 0,0,0);
        }
        ds += __shfl_xor(ds,16); ds += __shfl_xor(ds,32);
        dd += __shfl_xor(dd,16); dd += __shfl_xor(dd,32);
        if(g==0 && row0 < N){ ss[row0] = ds + c_s; sd[row0] = dd + c_d; }
        #pragma unroll
        for(int r=0;r<4;++r){
            int rr = rt*16 + g*4 + r;
            if(rr < N){
                short8 h;
                #pragma unroll
                for(int j=0;j<8;++j) h[j] = (short)f2bf(acc[j][r] + bb[j]);
                *(short8*)(Hp + (size_t)rr*D + t*8) = h;
            }
        }
    }
}

// P1: per-block LDS histogram over coarse buckets (dst>>6); M[bucket][blk]
__global__ __launch_bounds__(256) void k_bcount(const int* __restrict__ dst,
        unsigned* __restrict__ M, int E, int NB, int CHUNK){
    __shared__ unsigned h[1600];
    for(int i=threadIdx.x;i<NB;i+=256) h[i]=0u;
    __syncthreads();
    int s = blockIdx.x*CHUNK;
    int e = s+CHUNK < E ? s+CHUNK : E;
    for(int i=s+(int)threadIdx.x;i<e;i+=256) atomicAdd(&h[((unsigned)dst[i])>>6],1u);
    __syncthreads();
    for(int i=threadIdx.x;i<NB;i+=256) M[(size_t)i*gridDim.x + blockIdx.x] = h[i];
}

// P2a: block sums of 4096-chunks
__global__ __launch_bounds__(256) void k_scanA(const unsigned* __restrict__ M,
        unsigned* __restrict__ bsum, int n){
    __shared__ unsigned lds[4];
    int base = blockIdx.x*4096 + threadIdx.x*16;
    unsigned s=0;
    #pragma unroll
    for(int k=0;k<16;++k){ int i=base+k; if(i<n) s+=M[i]; }
    #pragma unroll
    for(int o=1;o<64;o<<=1) s += __shfl_xor(s,o);
    if((threadIdx.x&63)==0) lds[threadIdx.x>>6]=s;
    __syncthreads();
    if(threadIdx.x==0) bsum[blockIdx.x] = lds[0]+lds[1]+lds[2]+lds[3];
}

// P2b: single-block in-place exclusive scan of block sums
__global__ __launch_bounds__(256) void k_scanB(unsigned* __restrict__ bsum, int nb){
    __shared__ unsigned lds[4];
    int t = threadIdx.x;
    int chunk = (nb+255)/256;
    int s0 = t*chunk, s1 = s0+chunk < nb ? s0+chunk : nb;
    unsigned tsum=0;
    for(int i=s0;i<s1;++i) tsum += bsum[i];
    unsigned x=tsum;
    #pragma unroll
    for(int o=1;o<64;o<<=1){ unsigned y=__shfl_up(x,(unsigned)o); if((t&63)>=o) x+=y; }
    if((t&63)==63) lds[t>>6]=x;
    __syncthreads();
    unsigned woff=0;
    for(int w=0;w<(t>>6);++w) woff+=lds[w];
    unsigned run = woff + (x - tsum);
    for(int i=s0;i<s1;++i){ unsigned vv=bsum[i]; bsum[i]=run; run+=vv; }
}

// P2c: per-block local exclusive scan + scanned block offset
__global__ __launch_bounds__(256) void k_scanC(const unsigned* __restrict__ M,
        const unsigned* __restrict__ bsum, unsigned* __restrict__ Msc, int n){
    __shared__ unsigned lds[4];
    int t = threadIdx.x;
    int base = blockIdx.x*4096 + t*16;
    unsigned v[16]; unsigned tsum=0;
    #pragma unroll
    for(int k=0;k<16;++k){ int i=base+k; v[k]=(i<n)?M[i]:0u; tsum+=v[k]; }
    unsigned x=tsum;
    #pragma unroll
    for(int o=1;o<64;o<<=1){ unsigned y=__shfl_up(x,(unsigned)o); if((t&63)>=o) x+=y; }
    if((t&63)==63) lds[t>>6]=x;
    __syncthreads();
    unsigned woff = bsum[blockIdx.x];
    for(int w=0;w<(t>>6);++w) woff+=lds[w];
    unsigned run = woff + (x - tsum);
    #pragma unroll
    for(int k=0;k<16;++k){ int i=base+k; if(i<n) Msc[i]=run; run+=v[k]; }
}

// P3: bucket-partition edges; slots via LDS atomics on scanned per-(block,bucket) bases
__global__ __launch_bounds__(256) void k_bscatter(const int* __restrict__ src,
        const int* __restrict__ dst, const unsigned* __restrict__ Msc,
        uint2* __restrict__ ew, int E, int NB, int CHUNK){
    __shared__ unsigned hoff[1600];
    int blk = blockIdx.x, NBLKg = gridDim.x;
    for(int i=threadIdx.x;i<NB;i+=256) hoff[i] = Msc[(size_t)i*NBLKg + blk];
    __syncthreads();
    int s = blk*CHUNK;
    int e = s+CHUNK < E ? s+CHUNK : E;
    for(int i=s+(int)threadIdx.x;i<e;i+=256){
        int d = dst[i];
        unsigned p = atomicAdd(&hoff[((unsigned)d)>>6], 1u);
        ew[p] = make_uint2((unsigned)src[i], (unsigned)d);
    }
}

// P4: per-bucket fine CSR (64 dsts): LDS count -> wave scan -> LDS-atomic rank
__global__ __launch_bounds__(256) void k_fine(const uint2* __restrict__ ew,
        const unsigned* __restrict__ Msc, unsigned* __restrict__ esrc,
        unsigned* __restrict__ offs, int N, int NB, int NBLKg, int E){
    __shared__ unsigned cA[64], cB[64], loff[64];
    __shared__ unsigned begS, endS;
    int b = blockIdx.x;
    int dbase = b<<6;
    if(threadIdx.x==0){
        begS = Msc[(size_t)b*NBLKg];
        endS = (b+1 < NB) ? Msc[(size_t)(b+1)*NBLKg] : (unsigned)E;
    }
    if(threadIdx.x<64){ cA[threadIdx.x]=0u; cB[threadIdx.x]=0u; }
    __syncthreads();
    const unsigned beg = begS, end = endS;
    for(unsigned i=beg+threadIdx.x; i<end; i+=256)
        atomicAdd(&cA[ew[i].y & 63], 1u);
    __syncthreads();
    if(threadIdx.x<64){
        unsigned c = cA[threadIdx.x];
        unsigned x = c;
        #pragma unroll
        for(int o=1;o<64;o<<=1){ unsigned y = __shfl_up(x,(unsigned)o); if((int)threadIdx.x>=o) x += y; }
        loff[threadIdx.x] = x - c;
        int dd = dbase + (int)threadIdx.x;
        if(dd < N) offs[dd] = beg + x - c;
    }
    if(b==0 && threadIdx.x==64) offs[N] = (unsigned)E;
    __syncthreads();
    for(unsigned i=beg+threadIdx.x; i<end; i+=256){
        uint2 p = ew[i];
        unsigned dl = p.y & 63;
        unsigned r = atomicAdd(&cB[dl], 1u);
        esrc[beg + loff[dl] + r] = p.x;
    }
}

// fused gather: 4 edges/iter, 16 lanes/edge, 16B/lane; 2-deep pipeline
__global__ __launch_bounds__(256) void k_gather(const unsigned* __restrict__ off,
        const unsigned* __restrict__ esrc, const float* __restrict__ ss,
        const float* __restrict__ sdv, const unsigned short* __restrict__ Hp,
        float* __restrict__ out, int N){
    const int wv = threadIdx.x>>6, l = threadIdx.x&63;
    const int d = blockIdx.x*4 + wv;
    if(d>=N) return;
    const int g = l>>4, t = l&15;
    const unsigned kb = off[d], ke = off[d+1];
    const float sdd = sdv[d];
    float acc[8];
    #pragma unroll
    for(int j=0;j<8;++j) acc[j]=0.f;
    float den = 0.f;

    unsigned eA = kb + g;
    unsigned eB = eA + 4;
    bool vA = eA < ke, vB = eB < ke;
    float ssA=0.f, ssB=0.f;
    uint4 uA = make_uint4(0u,0u,0u,0u), uB = make_uint4(0u,0u,0u,0u);
    if(vA){ unsigned s=esrc[eA]; ssA=ss[s]; uA=*(const uint4*)(Hp+(size_t)s*D+t*8); }
    if(vB){ unsigned s=esrc[eB]; ssB=ss[s]; uB=*(const uint4*)(Hp+(size_t)s*D+t*8); }
    while(vA){
        unsigned eC = eB + 4;
        bool vC = eC < ke;
        float ssC = 0.f; uint4 uC = make_uint4(0u,0u,0u,0u);
        if(vC){ unsigned s=esrc[eC]; ssC=ss[s]; uC=*(const uint4*)(Hp+(size_t)s*D+t*8); }
        float w = __expf(leaky(ssA + sdd));
        acc[0] = fmaf(w, __uint_as_float(uA.x<<16),        acc[0]);
        acc[1] = fmaf(w, __uint_as_float(uA.x&0xffff0000u),acc[1]);
        acc[2] = fmaf(w, __uint_as_float(uA.y<<16),        acc[2]);
        acc[3] = fmaf(w, __uint_as_float(uA.y&0xffff0000u),acc[3]);
        acc[4] = fmaf(w, __uint_as_float(uA.z<<16),        acc[4]);
        acc[5] = fmaf(w, __uint_as_float(uA.z&0xffff0000u),acc[5]);
        acc[6] = fmaf(w, __uint_as_float(uA.w<<16),        acc[6]);
        acc[7] = fmaf(w, __uint_as_float(uA.w&0xffff0000u),acc[7]);
        den += w;
        vA = vB; ssA = ssB; uA = uB;
        vB = vC; ssB = ssC; uB = uC;
        eB = eC;
    }
    #pragma unroll
    for(int j=0;j<8;++j){
        acc[j] += __shfl_xor(acc[j],16);
        acc[j] += __shfl_xor(acc[j],32);
    }
    den += __shfl_xor(den,16);
    den += __shfl_xor(den,32);
    float inv = 1.f/(den + 1e-9f);
    int c = g*32 + t;
    out[(size_t)d*D + c]      = acc[g*2]  * inv;
    out[(size_t)d*D + c + 16] = acc[g*2+1]* inv;
}

// out = leaky(f + h + (f*h)@W2^T + b2), in place on out
__global__ __launch_bounds__(256) void k_final(const float* __restrict__ F,
        const unsigned short* __restrict__ W2b, const float* __restrict__ b2,
        float* __restrict__ out, int N){
    const int lane = threadIdx.x & 63;
    const int wid  = blockIdx.x*4 + (threadIdx.x>>6);
    const int nw   = gridDim.x*4;
    const int t = lane & 15, g = lane >> 4;
    short8 wf[4][8];
    #pragma unroll
    for(int kk=0;kk<4;++kk)
      #pragma unroll
      for(int j=0;j<8;++j)
        wf[kk][j] = *(const short8*)(W2b + (size_t)(j*16+t)*D + kk*32 + g*8);
    float bb[8];
    #pragma unroll
    for(int j=0;j<8;++j) bb[j] = b2[j*16+t];
    const int Mt = (N+15)>>4;
    for(int rt = wid; rt < Mt; rt += nw){
        int row = rt*16 + t; if(row>=N) row = N-1;
        const float* fr = F   + (size_t)row*D + g*8;
        const float* hr = out + (size_t)row*D + g*8;
        f32x4 acc[8];
        #pragma unroll
        for(int j=0;j<8;++j) acc[j] = (f32x4){0.f,0.f,0.f,0.f};
        #pragma unroll
        for(int kk=0;kk<4;++kk){
            f32x4 flo = *(const f32x4*)(fr + kk*32);
            f32x4 fhi = *(const f32x4*)(fr + kk*32 + 4);
            f32x4 hlo = *(const f32x4*)(hr + kk*32);
            f32x4 hhi = *(const f32x4*)(hr + kk*32 + 4);
            short8 af;
            af[0]=(short)f2bf(flo[0]*hlo[0]); af[1]=(short)f2bf(flo[1]*hlo[1]);
            af[2]=(short)f2bf(flo[2]*hlo[2]); af[3]=(short)f2bf(flo[3]*hlo[3]);
            af[4]=(short)f2bf(fhi[0]*hhi[0]); af[5]=(short)f2bf(fhi[1]*hhi[1]);
            af[6]=(short)f2bf(fhi[2]*hhi[2]); af[7]=(short)f2bf(fhi[3]*hhi[3]);
            #pragma unroll
            for(int j=0;j<8;++j)
                acc[j] = __builtin_amdgcn_mfma_f32_16x16x32_bf16(af, wf[kk][j], acc[j], 0,0,0);
        }
        #pragma unroll
        for(int r=0;r<4;++r){
            int rr = rt*16 + g*4 + r;
            if(rr < N){
                #pragma unroll
                for(int j=0;j<8;++j){
                    int c = j*16 + t;
                    float f = F[(size_t)rr*D + c];
                    float h = out[(size_t)rr*D + c];
                    float val = f + h + acc[j][r] + bb[j];
                    out[(size_t)rr*D + c] = leaky(val);
                }
            }
        }
    }
}

extern "C" void kernel_launch(void* const* d_in, const int* in_sizes, int n_in,
                              void* d_out, int out_size, void* d_ws, size_t ws_size,
                              hipStream_t stream) {
    const int*   idx  = (const int*)  d_in[0];   // (2,E)
    const float* F    = (const float*)d_in[1];   // (N,128)
    const float* Waw  = (const float*)d_in[3];
    const float* Wab  = (const float*)d_in[4];
    const float* W1w  = (const float*)d_in[5];
    const float* W1b  = (const float*)d_in[6];
    const float* W2w  = (const float*)d_in[7];
    const float* W2b  = (const float*)d_in[8];
    const float* a    = (const float*)d_in[9];
    float* out = (float*)d_out;

    const int E = in_sizes[0]/2;
    const int N = in_sizes[1]/D;
    const int* srcp = idx;
    const int* dstp = idx + E;

    const int NBLK = 256;
    const int CHUNK = (E + NBLK - 1)/NBLK;
    const int NB = (N + 63)/64;            // coarse buckets (<=1600 by construction)
    const int NT = NB*NBLK;
    const int NSB = (NT + 4095)/4096;      // scan super-blocks

    unsigned short* Hp  = (unsigned short*)d_ws;           // N*128 bf16 (permuted rows)
    unsigned short* W1c = Hp + (size_t)N*D;                // 16384
    unsigned short* W2c = W1c + 16384;                     // 16384
    float*    ss   = (float*)(W2c + 16384);                // N
    float*    sd   = ss + N;                               // N
    float*    v    = sd + N;                               // 320
    unsigned* M    = (unsigned*)(v + 320);                 // NT
    unsigned* Msc  = M + NT;                               // NT+2
    unsigned* bsum = Msc + NT + 2;                         // NSB
    unsigned* offs = bsum + NSB + 2;                       // N+2
    unsigned* esrc = offs + (N+2);                         // E
    uint2*    ew   = (uint2*)(esrc + E + 2);               // E  (8B aligned)

    k_prep    <<<65, 256, 0, stream>>>(Waw, Wab, a, v, W1w, W2w, W1c, W2c);
    k_msgscal <<<512, 256, 0, stream>>>(F, W1c, W1b, v, Hp, ss, sd, N);
    k_bcount  <<<NBLK, 256, 0, stream>>>(dstp, M, E, NB, CHUNK);
    k_scanA   <<<NSB, 256, 0, stream>>>(M, bsum, NT);
    k_scanB   <<<1, 256, 0, stream>>>(bsum, NSB);
    k_scanC   <<<NSB, 256, 0, stream>>>(M, bsum, Msc, NT);
    k_bscatter<<<NBLK, 256, 0, stream>>>(srcp, dstp, Msc, ew, E, NB, CHUNK);
    k_fine    <<<NB, 256, 0, stream>>>(ew, Msc, esrc, offs, N, NB, NBLK, E);
    k_gather  <<<(N+3)/4, 256, 0, stream>>>(offs, esrc, ss, sd, Hp, out, N);
    k_final   <<<512, 256, 0, stream>>>(F, W2c, W2b, out, N);
}